// Round 21
// baseline (120.067 us; speedup 1.0000x reference)
//
#include <hip/hip_runtime.h>
#include <math.h>

#define B_ 16
#define N_ 4096

typedef __attribute__((ext_vector_type(8))) short short8v;
typedef __attribute__((ext_vector_type(4))) short short4v;
typedef __attribute__((ext_vector_type(4))) float f32x4;

__device__ __forceinline__ unsigned short f2bf(float f) {
  unsigned int u = __float_as_uint(f);
  return (unsigned short)((u + 0x7FFFu + ((u >> 16) & 1u)) >> 16);
}

__device__ __forceinline__ unsigned int pk2(float a, float b) {
  return (unsigned int)f2bf(a) | ((unsigned int)f2bf(b) << 16);
}

__device__ __forceinline__ short8v cvt8f(const float* p) {
  float4 a = *reinterpret_cast<const float4*>(p);
  float4 b = *reinterpret_cast<const float4*>(p + 4);
  short8v r;
  r[0] = (short)f2bf(a.x); r[1] = (short)f2bf(a.y);
  r[2] = (short)f2bf(a.z); r[3] = (short)f2bf(a.w);
  r[4] = (short)f2bf(b.x); r[5] = (short)f2bf(b.y);
  r[6] = (short)f2bf(b.z); r[7] = (short)f2bf(b.w);
  return r;
}

// ===== fused prep: x-transpose + bf16 row-copy (0..2047) + weight cvt ======
__global__ __launch_bounds__(256) void prep(const float* __restrict__ x,
    unsigned short* __restrict__ xT, unsigned short* __restrict__ xb,
    const float* __restrict__ a, const float* __restrict__ b,
    const float* __restrict__ c, const float* __restrict__ d,
    const float* __restrict__ s1, const float* __restrict__ s2,
    unsigned short* __restrict__ wa, unsigned short* __restrict__ wb,
    unsigned short* __restrict__ wc, unsigned short* __restrict__ wd,
    unsigned short* __restrict__ w1, unsigned short* __restrict__ w2) {
  __shared__ float lds[32 * 132];
  const int t = threadIdx.x;
  if (blockIdx.x < 2048) {
    const int bb = blockIdx.x >> 7, pt = blockIdx.x & 127;
    const int ptile = pt * 32;
    for (int i = t; i < 1024; i += 256) {
      int p = i >> 5, c4 = (i & 31) << 2;
      *reinterpret_cast<float4*>(&lds[p * 132 + c4]) =
          *reinterpret_cast<const float4*>(
              x + ((size_t)(bb * 4096 + ptile + p)) * 128 + c4);
    }
    __syncthreads();
    // bf16 row-major copy (coalesced uint2)
    for (int i = t; i < 1024; i += 256) {
      int p = i >> 5, c4 = (i & 31) << 2;
      const float* s = &lds[p * 132 + c4];
      uint2 u;
      u.x = pk2(s[0], s[1]);
      u.y = pk2(s[2], s[3]);
      *reinterpret_cast<uint2*>(
          xb + ((size_t)(bb * 4096 + ptile + p)) * 128 + c4) = u;
    }
    // transpose to xT
    const int ch = t >> 1, p0 = (t & 1) * 16;
    unsigned short* dst = xT + (size_t)bb * 524288 + ch * 4096 + ptile + p0;
    uint4 u0, u1;
    u0.x = pk2(lds[(p0 + 0) * 132 + ch], lds[(p0 + 1) * 132 + ch]);
    u0.y = pk2(lds[(p0 + 2) * 132 + ch], lds[(p0 + 3) * 132 + ch]);
    u0.z = pk2(lds[(p0 + 4) * 132 + ch], lds[(p0 + 5) * 132 + ch]);
    u0.w = pk2(lds[(p0 + 6) * 132 + ch], lds[(p0 + 7) * 132 + ch]);
    u1.x = pk2(lds[(p0 + 8) * 132 + ch], lds[(p0 + 9) * 132 + ch]);
    u1.y = pk2(lds[(p0 + 10) * 132 + ch], lds[(p0 + 11) * 132 + ch]);
    u1.z = pk2(lds[(p0 + 12) * 132 + ch], lds[(p0 + 13) * 132 + ch]);
    u1.w = pk2(lds[(p0 + 14) * 132 + ch], lds[(p0 + 15) * 132 + ch]);
    *reinterpret_cast<uint4*>(dst) = u0;
    *reinterpret_cast<uint4*>(dst + 8) = u1;
  } else {
    int i = (blockIdx.x - 2048) * 256 + t;
    if (i < 16384) wa[i] = f2bf(a[i]);
    else if (i < 32768) { int o = i - 16384; wb[o] = f2bf(b[o]); }
    else if (i < 49152) { int o = i - 32768; wc[o] = f2bf(c[o]); }
    else if (i < 65536) { int o = i - 49152; wd[o] = f2bf(d[o]); }
    else if (i < 65536 + 1048576) { int o = i - 65536; w1[o] = f2bf(s1[o]); }
    else { int o = i - 65536 - 1048576; w2[o] = f2bf(s2[o]); }  // 262144
  }
}

// ===== conv body (R13 exact, decoded indices) ==============================
template <int SRV, int KSP>
__device__ void conv_body(int bx, int by, const unsigned short* __restrict__ xT,
    const unsigned short* __restrict__ W, float* __restrict__ part) {
  constexpr int WP = 64 / SRV;
  constexpr int M = WP * WP;
  constexpr int ROWS = B_ * M;
  constexpr int SS = SRV * SRV;
  constexpr int KTOT = 128 * SS;
  constexpr int LSS = (SRV == 8) ? 6 : 4;
  constexpr int LM = (SRV == 8) ? 6 : 8;
  constexpr int LWP = (SRV == 8) ? 3 : 4;
  const int t = threadIdx.x;
  const int wid = t >> 6, lane = t & 63;
  const int lrow = lane & 15, lk = (lane >> 4) << 3;
  const int r0 = bx * 128 + wid * 32;
  const int kb0 = by * KSP;
  int rbase[2], pixoff[2];
#pragma unroll
  for (int m = 0; m < 2; m++) {
    int row = r0 + m * 16 + lrow;
    int b = row >> LM, p = row & (M - 1);
    int ph = p >> LWP, pw = p & (WP - 1);
    rbase[m] = b << 19;
    pixoff[m] = (ph * SRV) * 64 + pw * SRV;
  }
  f32x4 acc[2][8];
#pragma unroll
  for (int m = 0; m < 2; m++)
#pragma unroll
    for (int n = 0; n < 8; n++) acc[m][n] = (f32x4)(0.f);
  for (int k0 = 0; k0 < KSP; k0 += 32) {
    int k = kb0 + k0 + lk;
    int ci = k >> LSS;
    int rem = k & (SS - 1);
    short8v a[2], bf[8];
#pragma unroll
    for (int m = 0; m < 2; m++) {
      if constexpr (SRV == 8) {
        a[m] = *reinterpret_cast<const short8v*>(
            xT + (size_t)rbase[m] + ci * 4096 + pixoff[m] + (rem >> 3) * 64);
      } else {
        int kh0 = rem >> 2;
        short4v lo = *reinterpret_cast<const short4v*>(
            xT + (size_t)rbase[m] + ci * 4096 + pixoff[m] + kh0 * 64);
        short4v hi = *reinterpret_cast<const short4v*>(
            xT + (size_t)rbase[m] + ci * 4096 + pixoff[m] + (kh0 + 1) * 64);
        short8v av;
        av[0] = lo[0]; av[1] = lo[1]; av[2] = lo[2]; av[3] = lo[3];
        av[4] = hi[0]; av[5] = hi[1]; av[6] = hi[2]; av[7] = hi[3];
        a[m] = av;
      }
    }
#pragma unroll
    for (int n = 0; n < 8; n++)
      bf[n] = *reinterpret_cast<const short8v*>(
          W + (size_t)(n * 16 + lrow) * KTOT + k);
#pragma unroll
    for (int m = 0; m < 2; m++)
#pragma unroll
      for (int n = 0; n < 8; n++)
        acc[m][n] = __builtin_amdgcn_mfma_f32_16x16x32_bf16(a[m], bf[n],
                                                            acc[m][n], 0, 0, 0);
  }
  const int rr = (lane >> 4) << 2;
#pragma unroll
  for (int m = 0; m < 2; m++)
#pragma unroll
    for (int n = 0; n < 8; n++) {
      int cc = n * 16 + lrow;
#pragma unroll
      for (int j = 0; j < 4; j++)
        part[((size_t)by * ROWS + r0 + m * 16 + rr + j) * 128 + cc] =
            acc[m][n][j];
    }
}

// ===== square GEMM body (R13 exact) ========================================
template <bool A_BF16, bool OUT_BF16, bool HAS_BIAS>
__device__ void gemm_body(int bx, const void* __restrict__ Araw,
    const unsigned short* __restrict__ W, const float* __restrict__ bias,
    void* __restrict__ out) {
  const int t = threadIdx.x;
  const int wid = t >> 6, lane = t & 63;
  const int lrow = lane & 15, lk = (lane >> 4) << 3;
  const int r0 = bx * 128 + wid * 32;
  f32x4 acc[2][8];
#pragma unroll
  for (int m = 0; m < 2; m++)
#pragma unroll
    for (int n = 0; n < 8; n++) acc[m][n] = (f32x4)(0.f);
#pragma unroll
  for (int k0 = 0; k0 < 128; k0 += 32) {
    short8v a[2], bf[8];
#pragma unroll
    for (int m = 0; m < 2; m++) {
      if constexpr (A_BF16)
        a[m] = *reinterpret_cast<const short8v*>(
            (const unsigned short*)Araw + (size_t)(r0 + m * 16 + lrow) * 128 +
            k0 + lk);
      else
        a[m] = cvt8f((const float*)Araw + (size_t)(r0 + m * 16 + lrow) * 128 +
                     k0 + lk);
    }
#pragma unroll
    for (int n = 0; n < 8; n++)
      bf[n] = *reinterpret_cast<const short8v*>(
          W + (size_t)(n * 16 + lrow) * 128 + k0 + lk);
#pragma unroll
    for (int m = 0; m < 2; m++)
#pragma unroll
      for (int n = 0; n < 8; n++)
        acc[m][n] = __builtin_amdgcn_mfma_f32_16x16x32_bf16(a[m], bf[n],
                                                            acc[m][n], 0, 0, 0);
  }
  const int rr = (lane >> 4) << 2;
#pragma unroll
  for (int m = 0; m < 2; m++)
#pragma unroll
    for (int n = 0; n < 8; n++) {
      int cc = n * 16 + lrow;
      float bv = HAS_BIAS ? bias[cc] : 0.f;
#pragma unroll
      for (int j = 0; j < 4; j++) {
        size_t idx = (size_t)(r0 + m * 16 + rr + j) * 128 + cc;
        float v = acc[m][n][j] + bv;
        if constexpr (OUT_BF16)
          ((unsigned short*)out)[idx] = f2bf(v);
        else
          ((float*)out)[idx] = v;
      }
    }
}

// ===== fused conv1 + conv2 + q-gemm (KSP=512; q-gemm IN-PLACE on xb) =======
__global__ __launch_bounds__(256) void conv_q(
    const unsigned short* __restrict__ xT, const unsigned short* __restrict__ w1b,
    const unsigned short* __restrict__ w2b, float* __restrict__ part1,
    float* __restrict__ part2, unsigned short* __restrict__ xb,
    const unsigned short* __restrict__ wq) {
  const int bid = blockIdx.x;
  if (bid < 128) {
    conv_body<8, 512>(bid & 7, bid >> 3, xT, w1b, part1);
  } else if (bid < 256) {
    int j = bid - 128;
    conv_body<4, 512>(j & 31, j >> 5, xT, w2b, part2);
  } else {
    // in-place: block reads rows [r0,r0+128) of xb fully, then writes them
    gemm_body<true, true, false>(bid - 256, xb, wq, nullptr, xb);
  }
}

// ===== fused LN+GELU over both branches (nsplit 16 / 4) ====================
__global__ __launch_bounds__(128) void ln_all(const float* __restrict__ part1,
    const float* __restrict__ part2, const float* __restrict__ cb1,
    const float* __restrict__ g1, const float* __restrict__ be1,
    const float* __restrict__ cb2, const float* __restrict__ g2,
    const float* __restrict__ be2, unsigned short* __restrict__ out1,
    unsigned short* __restrict__ out2) {
  const int t = threadIdx.x;
  int row = blockIdx.x;
  const float* part; const float *cb, *g, *be; unsigned short* out;
  int nsplit, rows;
  if (row < 1024) {
    part = part1; cb = cb1; g = g1; be = be1; out = out1;
    nsplit = 16; rows = 1024;
  } else {
    row -= 1024;
    part = part2; cb = cb2; g = g2; be = be2; out = out2;
    nsplit = 4; rows = 4096;
  }
  float v = cb[t];
  for (int s = 0; s < nsplit; s++)
    v += part[((size_t)s * rows + row) * 128 + t];
  float sv = v, sq = v * v;
#pragma unroll
  for (int off = 32; off > 0; off >>= 1) {
    sv += __shfl_down(sv, off, 64);
    sq += __shfl_down(sq, off, 64);
  }
  __shared__ float red0[2], red1[2];
  if ((t & 63) == 0) {
    red0[t >> 6] = sv;
    red1[t >> 6] = sq;
  }
  __syncthreads();
  float mean = (red0[0] + red0[1]) * (1.f / 128.f);
  float var = (red1[0] + red1[1]) * (1.f / 128.f) - mean * mean;
  float y = (v - mean) * rsqrtf(var + 1e-5f) * g[t] + be[t];
  out[(size_t)row * 128 + t] = f2bf(y * 0.5f * (1.f + erff(y * 0.70710678118f)));
}

// ===== kv GEMM body (split epilogue, R13 exact) ============================
__device__ void kv_body(int bx, const unsigned short* __restrict__ A,
    const unsigned short* __restrict__ W, unsigned short* __restrict__ kb,
    float* __restrict__ vr) {
  const int t = threadIdx.x;
  const int wid = t >> 6, lane = t & 63;
  const int lrow = lane & 15, lk = (lane >> 4) << 3;
  const int r0 = bx * 128 + wid * 32;
  f32x4 acc[2][8];
#pragma unroll
  for (int m = 0; m < 2; m++)
#pragma unroll
    for (int n = 0; n < 8; n++) acc[m][n] = (f32x4)(0.f);
#pragma unroll
  for (int k0 = 0; k0 < 128; k0 += 32) {
    short8v a[2], bf[8];
#pragma unroll
    for (int m = 0; m < 2; m++)
      a[m] = *reinterpret_cast<const short8v*>(
          A + (size_t)(r0 + m * 16 + lrow) * 128 + k0 + lk);
#pragma unroll
    for (int n = 0; n < 8; n++)
      bf[n] = *reinterpret_cast<const short8v*>(
          W + (size_t)(n * 16 + lrow) * 128 + k0 + lk);
#pragma unroll
    for (int m = 0; m < 2; m++)
#pragma unroll
      for (int n = 0; n < 8; n++)
        acc[m][n] = __builtin_amdgcn_mfma_f32_16x16x32_bf16(a[m], bf[n],
                                                            acc[m][n], 0, 0, 0);
  }
  const int rr = (lane >> 4) << 2;
#pragma unroll
  for (int m = 0; m < 2; m++)
#pragma unroll
    for (int n = 0; n < 8; n++) {
      int cc = n * 16 + lrow;
#pragma unroll
      for (int j = 0; j < 4; j++) {
        int r = r0 + m * 16 + rr + j;
        float v = acc[m][n][j];
        if (cc < 64)
          kb[(size_t)r * 64 + cc] = f2bf(v);
        else
          vr[(size_t)r * 64 + (cc - 64)] = v;
      }
    }
}

__global__ __launch_bounds__(256) void kv_all(
    const unsigned short* __restrict__ t1b, const unsigned short* __restrict__ wkv1,
    unsigned short* __restrict__ kb1, float* __restrict__ vr1,
    const unsigned short* __restrict__ t2b, const unsigned short* __restrict__ wkv2,
    unsigned short* __restrict__ kb2, float* __restrict__ vr2) {
  if (blockIdx.x < 8)
    kv_body(blockIdx.x, t1b, wkv1, kb1, vr1);
  else
    kv_body(blockIdx.x - 8, t2b, wkv2, kb2, vr2);
}

// ===== dwconv body (R13 exact) =============================================
template <int WP>
__device__ void dw_body(int idx, const float* __restrict__ vr,
    const float* __restrict__ lw, const float* __restrict__ lb,
    float* __restrict__ vp) {
  constexpr int M = WP * WP;
  constexpr int LM = (WP == 8) ? 6 : 8;
  constexpr int LWPc = (WP == 8) ? 3 : 4;
  int ch = idx & 63;
  int rest = idx >> 6;
  int m = rest & (M - 1);
  int bb = rest >> LM;
  int y = m >> LWPc, x0 = m & (WP - 1);
  float s = lb[ch];
#pragma unroll
  for (int ky = 0; ky < 3; ky++) {
    int yy = y + ky - 1;
    if (yy < 0 || yy >= WP) continue;
#pragma unroll
    for (int kx = 0; kx < 3; kx++) {
      int xx = x0 + kx - 1;
      if (xx < 0 || xx >= WP) continue;
      s += vr[((size_t)(bb * M + yy * WP + xx)) * 64 + ch] *
           lw[ch * 9 + ky * 3 + kx];
    }
  }
  vp[idx] = vr[((size_t)(bb * M + m)) * 64 + ch] + s;
}

__global__ __launch_bounds__(256) void dw_all(const float* __restrict__ vr1,
    const float* __restrict__ lw1, const float* __restrict__ lb1,
    float* __restrict__ v1p, const float* __restrict__ vr2,
    const float* __restrict__ lw2, const float* __restrict__ lb2,
    float* __restrict__ v2p) {
  if (blockIdx.x < 256)
    dw_body<8>(blockIdx.x * 256 + threadIdx.x, vr1, lw1, lb1, v1p);
  else
    dw_body<16>((blockIdx.x - 256) * 256 + threadIdx.x, vr2, lw2, lb2, v2p);
}

// ===== v-transpose body (R13 exact) ========================================
template <int M>
__device__ void tv_body(int blk, const float* __restrict__ vp,
    unsigned short* __restrict__ vT, float* lds) {
  constexpr int TPB = M / 32;
  const int t = threadIdx.x;
  const int b = blk / TPB, mt = blk % TPB;
  const int m0 = mt * 32;
  for (int i = t; i < 512; i += 256) {
    int m = i >> 4, c4 = (i & 15) << 2;
    *reinterpret_cast<float4*>(&lds[m * 68 + c4]) =
        *reinterpret_cast<const float4*>(vp + ((size_t)(b * M + m0 + m)) * 64 + c4);
  }
  __syncthreads();
  const int c = t >> 2, ms = (t & 3) * 8;
  unsigned short* dst = vT + ((size_t)b * 64 + c) * M + m0 + ms;
  uint4 u;
  u.x = pk2(lds[(ms + 0) * 68 + c], lds[(ms + 1) * 68 + c]);
  u.y = pk2(lds[(ms + 2) * 68 + c], lds[(ms + 3) * 68 + c]);
  u.z = pk2(lds[(ms + 4) * 68 + c], lds[(ms + 5) * 68 + c]);
  u.w = pk2(lds[(ms + 6) * 68 + c], lds[(ms + 7) * 68 + c]);
  *reinterpret_cast<uint4*>(dst) = u;
}

__global__ __launch_bounds__(256) void tv_all(const float* __restrict__ v1p,
    unsigned short* __restrict__ vT1, const float* __restrict__ v2p,
    unsigned short* __restrict__ vT2) {
  __shared__ float lds[32 * 68];
  if (blockIdx.x < 32)
    tv_body<64>(blockIdx.x, v1p, vT1, lds);
  else
    tv_body<256>(blockIdx.x - 32, v2p, vT2, lds);
}

// ===== attention: M=256 heads use LDS-staged K; M=64 heads read K global ===
template <int M, int QOFF, bool K_LDS>
__device__ void attn_head(int b, int q0, int h,
    const unsigned short* __restrict__ qb, const unsigned short* Ks,
    const unsigned short* __restrict__ kbg, const unsigned short* __restrict__ vT,
    unsigned short* __restrict__ xc, unsigned short* Plw) {
  constexpr int HM = (M > 128) ? 128 : M;
  constexpr int NCH = M / HM;
  constexpr int PSTR = HM + 8;
  constexpr int MT = M / 16;
  constexpr int HKS = HM / 32;
  const int lane = threadIdx.x & 63;
  const int lrow = lane & 15, g = lane >> 4;
  const int lk = g * 8;
  const size_t bm = (size_t)b * M;
  const size_t qrow = ((size_t)b * 4096 + q0 + lrow) * 128;
  const int qoff = QOFF + h * 32;
  const float scale = 0.17677669529663687f;  // 1/sqrt(32)
  short8v qf = *reinterpret_cast<const short8v*>(qb + qrow + qoff + lk);
  f32x4 s[MT];
#pragma unroll
  for (int mt = 0; mt < MT; mt++) {
    short8v kf;
    if constexpr (K_LDS)
      kf = *reinterpret_cast<const short8v*>(
          Ks + (mt * 16 + lrow) * 72 + h * 32 + lk);
    else
      kf = *reinterpret_cast<const short8v*>(
          kbg + (bm + mt * 16 + lrow) * 64 + h * 32 + lk);
    s[mt] =
        __builtin_amdgcn_mfma_f32_16x16x32_bf16(kf, qf, (f32x4)(0.f), 0, 0, 0);
  }
  float l = 0.f;
#pragma unroll
  for (int mt = 0; mt < MT; mt++)
#pragma unroll
    for (int j = 0; j < 4; j++) {
      float p = __expf(s[mt][j] * scale);
      s[mt][j] = p;
      l += p;
    }
  l += __shfl_xor(l, 16, 64);
  l += __shfl_xor(l, 32, 64);
  f32x4 o[2];
  o[0] = (f32x4)(0.f);
  o[1] = (f32x4)(0.f);
#pragma unroll
  for (int half = 0; half < NCH; half++) {
#pragma unroll
    for (int mt2 = 0; mt2 < HM / 16; mt2++) {
      int mt = half * (HM / 16) + mt2;
      uint2 pw;
      pw.x = pk2(s[mt][0], s[mt][1]);
      pw.y = pk2(s[mt][2], s[mt][3]);
      *reinterpret_cast<uint2*>(&Plw[lrow * PSTR + mt2 * 16 + 4 * g]) = pw;
    }
    f32x4 oh[2];
    oh[0] = (f32x4)(0.f);
    oh[1] = (f32x4)(0.f);
#pragma unroll
    for (int ks = 0; ks < HKS; ks++) {
      short8v pf = *reinterpret_cast<const short8v*>(
          &Plw[lrow * PSTR + ks * 32 + lk]);
#pragma unroll
      for (int dt = 0; dt < 2; dt++) {
        short8v vf = *reinterpret_cast<const short8v*>(
            vT + ((size_t)b * 64 + h * 32 + dt * 16 + lrow) * M + half * HM +
            ks * 32 + lk);
        oh[dt] =
            __builtin_amdgcn_mfma_f32_16x16x32_bf16(vf, pf, oh[dt], 0, 0, 0);
      }
    }
#pragma unroll
    for (int dt = 0; dt < 2; dt++) o[dt] += oh[dt];
  }
  float linv = 1.f / l;
  unsigned short* orow = xc + qrow + qoff;
#pragma unroll
  for (int dt = 0; dt < 2; dt++) {
    uint2 u;
    u.x = pk2(o[dt][0] * linv, o[dt][1] * linv);
    u.y = pk2(o[dt][2] * linv, o[dt][3] * linv);
    *reinterpret_cast<uint2*>(orow + dt * 16 + 4 * g) = u;
  }
}

// one block per (b, 64 q-rows); 4 heads; only K2 staged (LDS 53 KiB -> 3/CU)
__global__ __launch_bounds__(256) void attn_all(
    const unsigned short* __restrict__ qb, const unsigned short* __restrict__ kb1,
    const unsigned short* __restrict__ vT1, const unsigned short* __restrict__ kb2,
    const unsigned short* __restrict__ vT2, unsigned short* __restrict__ xc) {
  __shared__ unsigned short Ks2[256 * 72];      // 36 KiB
  __shared__ unsigned short Pl[4 * 16 * 136];   // 17 KiB
  const int t = threadIdx.x;
  const int b = blockIdx.x >> 6, qt = blockIdx.x & 63;
  for (int i = t; i < 2048; i += 256) {
    int row = i >> 3, seg = i & 7;
    *reinterpret_cast<uint4*>(&Ks2[row * 72 + seg * 8]) =
        *reinterpret_cast<const uint4*>(kb2 + ((size_t)b * 256 + row) * 64 +
                                        seg * 8);
  }
  __syncthreads();
  const int wid = t >> 6;
  unsigned short* Plw = Pl + wid * 16 * 136;
  const int q0 = qt * 64 + wid * 16;
  attn_head<256, 64, true>(b, q0, 0, qb, Ks2, nullptr, vT2, xc, Plw);
  attn_head<256, 64, true>(b, q0, 1, qb, Ks2, nullptr, vT2, xc, Plw);
  attn_head<64, 0, false>(b, q0, 0, qb, nullptr, kb1, vT1, xc, Plw);
  attn_head<64, 0, false>(b, q0, 1, qb, nullptr, kb1, vT1, xc, Plw);
}

// ===== output projection ===================================================
__global__ __launch_bounds__(256) void proj(const unsigned short* __restrict__ A,
    const unsigned short* __restrict__ W, const float* __restrict__ bias,
    float* __restrict__ out) {
  gemm_body<true, false, true>(blockIdx.x, A, W, bias, out);
}

extern "C" void kernel_launch(void* const* d_in, const int* in_sizes, int n_in,
                              void* d_out, int out_size, void* d_ws,
                              size_t ws_size, hipStream_t stream) {
  (void)in_sizes; (void)n_in; (void)out_size; (void)ws_size;
  const float* x      = (const float*)d_in[0];
  const float* q_w    = (const float*)d_in[1];
  const float* sr1_w  = (const float*)d_in[2];
  const float* sr1_b  = (const float*)d_in[3];
  const float* n1_g   = (const float*)d_in[4];
  const float* n1_b   = (const float*)d_in[5];
  const float* sr2_w  = (const float*)d_in[6];
  const float* sr2_b  = (const float*)d_in[7];
  const float* n2_g   = (const float*)d_in[8];
  const float* n2_b   = (const float*)d_in[9];
  const float* kv1_w  = (const float*)d_in[10];
  const float* kv2_w  = (const float*)d_in[11];
  const float* lc1_w  = (const float*)d_in[12];
  const float* lc1_b  = (const float*)d_in[13];
  const float* lc2_w  = (const float*)d_in[14];
  const float* lc2_b  = (const float*)d_in[15];
  const float* proj_w = (const float*)d_in[16];
  const float* proj_b = (const float*)d_in[17];

  char* w = (char*)d_ws;
  unsigned short* wq    = (unsigned short*)(w);             // 32 KB
  unsigned short* wkv1  = (unsigned short*)(w + 32768);
  unsigned short* wkv2  = (unsigned short*)(w + 65536);
  unsigned short* wproj = (unsigned short*)(w + 98304);     // ends 131072
  unsigned short* w1b   = (unsigned short*)(w + 131072);    // 2 MB   -> 2228224
  unsigned short* w2b   = (unsigned short*)(w + 2228224);   // 512 KB -> 2752512
  unsigned short* xT  = (unsigned short*)(w + 2752512);     // 16.78 MB -> 19529728
  unsigned short* kb1 = (unsigned short*)(w + 19529728);    // 128 KB -> 19660800
  unsigned short* kb2 = (unsigned short*)(w + 19660800);    // 512 KB -> 20185088
  float* part1 = (float*)(w + 33685504);                    // 8.39 MB -> 42074112
  float* part2 = (float*)(w + 42074112);                    // 8.39 MB -> 50462720
  unsigned short* xcb = (unsigned short*)(w + 33685504);    // 16.78 MB (after ln)
  // xb: written by prep; q-GEMM transforms it IN PLACE into q (bf16).
  unsigned short* xb  = (unsigned short*)(w + 50462720);    // 16.78 MB -> 67239936
  unsigned short* qb  = xb;                                 // same buffer
  unsigned short* t1b = (unsigned short*)(w + 69468160);    // 256 KB -> 69730304
  unsigned short* t2b = (unsigned short*)(w + 69730304);    // 1 MB  -> 70778880
  float* vr1 = (float*)(w + 70778880);                      // 256 KB -> 71041024
  float* vr2 = (float*)(w + 71041024);                      // 1 MB  -> 72089600
  float* v1p = (float*)(w + 72089600);                      // 256 KB -> 72351744
  float* v2p = (float*)(w + 72351744);                      // 1 MB  -> 73400320
  unsigned short* vT1 = (unsigned short*)(w + 73400320);    // 128 KB -> 73531392
  unsigned short* vT2 = (unsigned short*)(w + 73531392);    // 512 KB -> 74055680

  prep<<<7424, 256, 0, stream>>>(x, xT, xb, q_w, kv1_w, kv2_w, proj_w, sr1_w,
                                 sr2_w, wq, wkv1, wkv2, wproj, w1b, w2b);
  conv_q<<<768, 256, 0, stream>>>(xT, w1b, w2b, part1, part2, xb, wq);
  ln_all<<<5120, 128, 0, stream>>>(part1, part2, sr1_b, n1_g, n1_b, sr2_b, n2_g,
                                   n2_b, t1b, t2b);
  kv_all<<<40, 256, 0, stream>>>(t1b, wkv1, kb1, vr1, t2b, wkv2, kb2, vr2);
  dw_all<<<1280, 256, 0, stream>>>(vr1, lc1_w, lc1_b, v1p, vr2, lc2_w, lc2_b, v2p);
  tv_all<<<160, 256, 0, stream>>>(v1p, vT1, v2p, vT2);
  attn_all<<<1024, 256, 0, stream>>>(qb, kb1, vT1, kb2, vT2, xcb);
  proj<<<512, 256, 0, stream>>>(xcb, wproj, proj_b, (float*)d_out);
}

// Round 22
// 118.744 us; speedup vs baseline: 1.0111x; 1.0111x over previous
//
#include <hip/hip_runtime.h>
#include <math.h>

#define B_ 16
#define N_ 4096

typedef __attribute__((ext_vector_type(8))) short short8v;
typedef __attribute__((ext_vector_type(4))) short short4v;
typedef __attribute__((ext_vector_type(4))) float f32x4;

__device__ __forceinline__ unsigned short f2bf(float f) {
  unsigned int u = __float_as_uint(f);
  return (unsigned short)((u + 0x7FFFu + ((u >> 16) & 1u)) >> 16);
}

__device__ __forceinline__ unsigned int pk2(float a, float b) {
  return (unsigned int)f2bf(a) | ((unsigned int)f2bf(b) << 16);
}

__device__ __forceinline__ short8v cvt8f(const float* p) {
  float4 a = *reinterpret_cast<const float4*>(p);
  float4 b = *reinterpret_cast<const float4*>(p + 4);
  short8v r;
  r[0] = (short)f2bf(a.x); r[1] = (short)f2bf(a.y);
  r[2] = (short)f2bf(a.z); r[3] = (short)f2bf(a.w);
  r[4] = (short)f2bf(b.x); r[5] = (short)f2bf(b.y);
  r[6] = (short)f2bf(b.z); r[7] = (short)f2bf(b.w);
  return r;
}

// ===== fused prep: x-transpose + bf16 row-copy (0..2047) + weight cvt ======
__global__ __launch_bounds__(256) void prep(const float* __restrict__ x,
    unsigned short* __restrict__ xT, unsigned short* __restrict__ xb,
    const float* __restrict__ a, const float* __restrict__ b,
    const float* __restrict__ c, const float* __restrict__ d,
    const float* __restrict__ s1, const float* __restrict__ s2,
    unsigned short* __restrict__ wa, unsigned short* __restrict__ wb,
    unsigned short* __restrict__ wc, unsigned short* __restrict__ wd,
    unsigned short* __restrict__ w1, unsigned short* __restrict__ w2) {
  __shared__ float lds[32 * 132];
  const int t = threadIdx.x;
  if (blockIdx.x < 2048) {
    const int bb = blockIdx.x >> 7, pt = blockIdx.x & 127;
    const int ptile = pt * 32;
    for (int i = t; i < 1024; i += 256) {
      int p = i >> 5, c4 = (i & 31) << 2;
      *reinterpret_cast<float4*>(&lds[p * 132 + c4]) =
          *reinterpret_cast<const float4*>(
              x + ((size_t)(bb * 4096 + ptile + p)) * 128 + c4);
    }
    __syncthreads();
    // bf16 row-major copy (coalesced uint2)
    for (int i = t; i < 1024; i += 256) {
      int p = i >> 5, c4 = (i & 31) << 2;
      const float* s = &lds[p * 132 + c4];
      uint2 u;
      u.x = pk2(s[0], s[1]);
      u.y = pk2(s[2], s[3]);
      *reinterpret_cast<uint2*>(
          xb + ((size_t)(bb * 4096 + ptile + p)) * 128 + c4) = u;
    }
    // transpose to xT
    const int ch = t >> 1, p0 = (t & 1) * 16;
    unsigned short* dst = xT + (size_t)bb * 524288 + ch * 4096 + ptile + p0;
    uint4 u0, u1;
    u0.x = pk2(lds[(p0 + 0) * 132 + ch], lds[(p0 + 1) * 132 + ch]);
    u0.y = pk2(lds[(p0 + 2) * 132 + ch], lds[(p0 + 3) * 132 + ch]);
    u0.z = pk2(lds[(p0 + 4) * 132 + ch], lds[(p0 + 5) * 132 + ch]);
    u0.w = pk2(lds[(p0 + 6) * 132 + ch], lds[(p0 + 7) * 132 + ch]);
    u1.x = pk2(lds[(p0 + 8) * 132 + ch], lds[(p0 + 9) * 132 + ch]);
    u1.y = pk2(lds[(p0 + 10) * 132 + ch], lds[(p0 + 11) * 132 + ch]);
    u1.z = pk2(lds[(p0 + 12) * 132 + ch], lds[(p0 + 13) * 132 + ch]);
    u1.w = pk2(lds[(p0 + 14) * 132 + ch], lds[(p0 + 15) * 132 + ch]);
    *reinterpret_cast<uint4*>(dst) = u0;
    *reinterpret_cast<uint4*>(dst + 8) = u1;
  } else {
    int i = (blockIdx.x - 2048) * 256 + t;
    if (i < 16384) wa[i] = f2bf(a[i]);
    else if (i < 32768) { int o = i - 16384; wb[o] = f2bf(b[o]); }
    else if (i < 49152) { int o = i - 32768; wc[o] = f2bf(c[o]); }
    else if (i < 65536) { int o = i - 49152; wd[o] = f2bf(d[o]); }
    else if (i < 65536 + 1048576) { int o = i - 65536; w1[o] = f2bf(s1[o]); }
    else { int o = i - 65536 - 1048576; w2[o] = f2bf(s2[o]); }  // 262144
  }
}

// ===== conv body (R13 exact, decoded indices) ==============================
template <int SRV, int KSP>
__device__ void conv_body(int bx, int by, const unsigned short* __restrict__ xT,
    const unsigned short* __restrict__ W, float* __restrict__ part) {
  constexpr int WP = 64 / SRV;
  constexpr int M = WP * WP;
  constexpr int ROWS = B_ * M;
  constexpr int SS = SRV * SRV;
  constexpr int KTOT = 128 * SS;
  constexpr int LSS = (SRV == 8) ? 6 : 4;
  constexpr int LM = (SRV == 8) ? 6 : 8;
  constexpr int LWP = (SRV == 8) ? 3 : 4;
  const int t = threadIdx.x;
  const int wid = t >> 6, lane = t & 63;
  const int lrow = lane & 15, lk = (lane >> 4) << 3;
  const int r0 = bx * 128 + wid * 32;
  const int kb0 = by * KSP;
  int rbase[2], pixoff[2];
#pragma unroll
  for (int m = 0; m < 2; m++) {
    int row = r0 + m * 16 + lrow;
    int b = row >> LM, p = row & (M - 1);
    int ph = p >> LWP, pw = p & (WP - 1);
    rbase[m] = b << 19;
    pixoff[m] = (ph * SRV) * 64 + pw * SRV;
  }
  f32x4 acc[2][8];
#pragma unroll
  for (int m = 0; m < 2; m++)
#pragma unroll
    for (int n = 0; n < 8; n++) acc[m][n] = (f32x4)(0.f);
  for (int k0 = 0; k0 < KSP; k0 += 32) {
    int k = kb0 + k0 + lk;
    int ci = k >> LSS;
    int rem = k & (SS - 1);
    short8v a[2], bf[8];
#pragma unroll
    for (int m = 0; m < 2; m++) {
      if constexpr (SRV == 8) {
        a[m] = *reinterpret_cast<const short8v*>(
            xT + (size_t)rbase[m] + ci * 4096 + pixoff[m] + (rem >> 3) * 64);
      } else {
        int kh0 = rem >> 2;
        short4v lo = *reinterpret_cast<const short4v*>(
            xT + (size_t)rbase[m] + ci * 4096 + pixoff[m] + kh0 * 64);
        short4v hi = *reinterpret_cast<const short4v*>(
            xT + (size_t)rbase[m] + ci * 4096 + pixoff[m] + (kh0 + 1) * 64);
        short8v av;
        av[0] = lo[0]; av[1] = lo[1]; av[2] = lo[2]; av[3] = lo[3];
        av[4] = hi[0]; av[5] = hi[1]; av[6] = hi[2]; av[7] = hi[3];
        a[m] = av;
      }
    }
#pragma unroll
    for (int n = 0; n < 8; n++)
      bf[n] = *reinterpret_cast<const short8v*>(
          W + (size_t)(n * 16 + lrow) * KTOT + k);
#pragma unroll
    for (int m = 0; m < 2; m++)
#pragma unroll
      for (int n = 0; n < 8; n++)
        acc[m][n] = __builtin_amdgcn_mfma_f32_16x16x32_bf16(a[m], bf[n],
                                                            acc[m][n], 0, 0, 0);
  }
  const int rr = (lane >> 4) << 2;
#pragma unroll
  for (int m = 0; m < 2; m++)
#pragma unroll
    for (int n = 0; n < 8; n++) {
      int cc = n * 16 + lrow;
#pragma unroll
      for (int j = 0; j < 4; j++)
        part[((size_t)by * ROWS + r0 + m * 16 + rr + j) * 128 + cc] =
            acc[m][n][j];
    }
}

// ===== square GEMM body (R13 exact) ========================================
template <bool A_BF16, bool OUT_BF16, bool HAS_BIAS>
__device__ void gemm_body(int bx, const void* __restrict__ Araw,
    const unsigned short* __restrict__ W, const float* __restrict__ bias,
    void* __restrict__ out) {
  const int t = threadIdx.x;
  const int wid = t >> 6, lane = t & 63;
  const int lrow = lane & 15, lk = (lane >> 4) << 3;
  const int r0 = bx * 128 + wid * 32;
  f32x4 acc[2][8];
#pragma unroll
  for (int m = 0; m < 2; m++)
#pragma unroll
    for (int n = 0; n < 8; n++) acc[m][n] = (f32x4)(0.f);
#pragma unroll
  for (int k0 = 0; k0 < 128; k0 += 32) {
    short8v a[2], bf[8];
#pragma unroll
    for (int m = 0; m < 2; m++) {
      if constexpr (A_BF16)
        a[m] = *reinterpret_cast<const short8v*>(
            (const unsigned short*)Araw + (size_t)(r0 + m * 16 + lrow) * 128 +
            k0 + lk);
      else
        a[m] = cvt8f((const float*)Araw + (size_t)(r0 + m * 16 + lrow) * 128 +
                     k0 + lk);
    }
#pragma unroll
    for (int n = 0; n < 8; n++)
      bf[n] = *reinterpret_cast<const short8v*>(
          W + (size_t)(n * 16 + lrow) * 128 + k0 + lk);
#pragma unroll
    for (int m = 0; m < 2; m++)
#pragma unroll
      for (int n = 0; n < 8; n++)
        acc[m][n] = __builtin_amdgcn_mfma_f32_16x16x32_bf16(a[m], bf[n],
                                                            acc[m][n], 0, 0, 0);
  }
  const int rr = (lane >> 4) << 2;
#pragma unroll
  for (int m = 0; m < 2; m++)
#pragma unroll
    for (int n = 0; n < 8; n++) {
      int cc = n * 16 + lrow;
      float bv = HAS_BIAS ? bias[cc] : 0.f;
#pragma unroll
      for (int j = 0; j < 4; j++) {
        size_t idx = (size_t)(r0 + m * 16 + rr + j) * 128 + cc;
        float v = acc[m][n][j] + bv;
        if constexpr (OUT_BF16)
          ((unsigned short*)out)[idx] = f2bf(v);
        else
          ((float*)out)[idx] = v;
      }
    }
}

// ===== fused conv1 + conv2 + q-gemm (KSP=512; q-gemm IN-PLACE on xb) =======
__global__ __launch_bounds__(256) void conv_q(
    const unsigned short* __restrict__ xT, const unsigned short* __restrict__ w1b,
    const unsigned short* __restrict__ w2b, float* __restrict__ part1,
    float* __restrict__ part2, unsigned short* __restrict__ xb,
    const unsigned short* __restrict__ wq) {
  const int bid = blockIdx.x;
  if (bid < 128) {
    conv_body<8, 512>(bid & 7, bid >> 3, xT, w1b, part1);
  } else if (bid < 256) {
    int j = bid - 128;
    conv_body<4, 512>(j & 31, j >> 5, xT, w2b, part2);
  } else {
    // in-place: block reads rows [r0,r0+128) of xb fully, then writes them
    gemm_body<true, true, false>(bid - 256, xb, wq, nullptr, xb);
  }
}

// ===== fused LN+GELU over both branches (nsplit 16 / 4) ====================
__global__ __launch_bounds__(128) void ln_all(const float* __restrict__ part1,
    const float* __restrict__ part2, const float* __restrict__ cb1,
    const float* __restrict__ g1, const float* __restrict__ be1,
    const float* __restrict__ cb2, const float* __restrict__ g2,
    const float* __restrict__ be2, unsigned short* __restrict__ out1,
    unsigned short* __restrict__ out2) {
  const int t = threadIdx.x;
  int row = blockIdx.x;
  const float* part; const float *cb, *g, *be; unsigned short* out;
  int nsplit, rows;
  if (row < 1024) {
    part = part1; cb = cb1; g = g1; be = be1; out = out1;
    nsplit = 16; rows = 1024;
  } else {
    row -= 1024;
    part = part2; cb = cb2; g = g2; be = be2; out = out2;
    nsplit = 4; rows = 4096;
  }
  float v = cb[t];
  for (int s = 0; s < nsplit; s++)
    v += part[((size_t)s * rows + row) * 128 + t];
  float sv = v, sq = v * v;
#pragma unroll
  for (int off = 32; off > 0; off >>= 1) {
    sv += __shfl_down(sv, off, 64);
    sq += __shfl_down(sq, off, 64);
  }
  __shared__ float red0[2], red1[2];
  if ((t & 63) == 0) {
    red0[t >> 6] = sv;
    red1[t >> 6] = sq;
  }
  __syncthreads();
  float mean = (red0[0] + red0[1]) * (1.f / 128.f);
  float var = (red1[0] + red1[1]) * (1.f / 128.f) - mean * mean;
  float y = (v - mean) * rsqrtf(var + 1e-5f) * g[t] + be[t];
  out[(size_t)row * 128 + t] = f2bf(y * 0.5f * (1.f + erff(y * 0.70710678118f)));
}

// ===== kv GEMM body (split epilogue, R13 exact) ============================
__device__ void kv_body(int bx, const unsigned short* __restrict__ A,
    const unsigned short* __restrict__ W, unsigned short* __restrict__ kb,
    float* __restrict__ vr) {
  const int t = threadIdx.x;
  const int wid = t >> 6, lane = t & 63;
  const int lrow = lane & 15, lk = (lane >> 4) << 3;
  const int r0 = bx * 128 + wid * 32;
  f32x4 acc[2][8];
#pragma unroll
  for (int m = 0; m < 2; m++)
#pragma unroll
    for (int n = 0; n < 8; n++) acc[m][n] = (f32x4)(0.f);
#pragma unroll
  for (int k0 = 0; k0 < 128; k0 += 32) {
    short8v a[2], bf[8];
#pragma unroll
    for (int m = 0; m < 2; m++)
      a[m] = *reinterpret_cast<const short8v*>(
          A + (size_t)(r0 + m * 16 + lrow) * 128 + k0 + lk);
#pragma unroll
    for (int n = 0; n < 8; n++)
      bf[n] = *reinterpret_cast<const short8v*>(
          W + (size_t)(n * 16 + lrow) * 128 + k0 + lk);
#pragma unroll
    for (int m = 0; m < 2; m++)
#pragma unroll
      for (int n = 0; n < 8; n++)
        acc[m][n] = __builtin_amdgcn_mfma_f32_16x16x32_bf16(a[m], bf[n],
                                                            acc[m][n], 0, 0, 0);
  }
  const int rr = (lane >> 4) << 2;
#pragma unroll
  for (int m = 0; m < 2; m++)
#pragma unroll
    for (int n = 0; n < 8; n++) {
      int cc = n * 16 + lrow;
#pragma unroll
      for (int j = 0; j < 4; j++) {
        int r = r0 + m * 16 + rr + j;
        float v = acc[m][n][j];
        if (cc < 64)
          kb[(size_t)r * 64 + cc] = f2bf(v);
        else
          vr[(size_t)r * 64 + (cc - 64)] = v;
      }
    }
}

__global__ __launch_bounds__(256) void kv_all(
    const unsigned short* __restrict__ t1b, const unsigned short* __restrict__ wkv1,
    unsigned short* __restrict__ kb1, float* __restrict__ vr1,
    const unsigned short* __restrict__ t2b, const unsigned short* __restrict__ wkv2,
    unsigned short* __restrict__ kb2, float* __restrict__ vr2) {
  if (blockIdx.x < 8)
    kv_body(blockIdx.x, t1b, wkv1, kb1, vr1);
  else
    kv_body(blockIdx.x - 8, t2b, wkv2, kb2, vr2);
}

// ===== dwconv body (R13 exact) =============================================
template <int WP>
__device__ void dw_body(int idx, const float* __restrict__ vr,
    const float* __restrict__ lw, const float* __restrict__ lb,
    float* __restrict__ vp) {
  constexpr int M = WP * WP;
  constexpr int LM = (WP == 8) ? 6 : 8;
  constexpr int LWPc = (WP == 8) ? 3 : 4;
  int ch = idx & 63;
  int rest = idx >> 6;
  int m = rest & (M - 1);
  int bb = rest >> LM;
  int y = m >> LWPc, x0 = m & (WP - 1);
  float s = lb[ch];
#pragma unroll
  for (int ky = 0; ky < 3; ky++) {
    int yy = y + ky - 1;
    if (yy < 0 || yy >= WP) continue;
#pragma unroll
    for (int kx = 0; kx < 3; kx++) {
      int xx = x0 + kx - 1;
      if (xx < 0 || xx >= WP) continue;
      s += vr[((size_t)(bb * M + yy * WP + xx)) * 64 + ch] *
           lw[ch * 9 + ky * 3 + kx];
    }
  }
  vp[idx] = vr[((size_t)(bb * M + m)) * 64 + ch] + s;
}

__global__ __launch_bounds__(256) void dw_all(const float* __restrict__ vr1,
    const float* __restrict__ lw1, const float* __restrict__ lb1,
    float* __restrict__ v1p, const float* __restrict__ vr2,
    const float* __restrict__ lw2, const float* __restrict__ lb2,
    float* __restrict__ v2p) {
  if (blockIdx.x < 256)
    dw_body<8>(blockIdx.x * 256 + threadIdx.x, vr1, lw1, lb1, v1p);
  else
    dw_body<16>((blockIdx.x - 256) * 256 + threadIdx.x, vr2, lw2, lb2, v2p);
}

// ===== v-transpose body (R13 exact) ========================================
template <int M>
__device__ void tv_body(int blk, const float* __restrict__ vp,
    unsigned short* __restrict__ vT, float* lds) {
  constexpr int TPB = M / 32;
  const int t = threadIdx.x;
  const int b = blk / TPB, mt = blk % TPB;
  const int m0 = mt * 32;
  for (int i = t; i < 512; i += 256) {
    int m = i >> 4, c4 = (i & 15) << 2;
    *reinterpret_cast<float4*>(&lds[m * 68 + c4]) =
        *reinterpret_cast<const float4*>(vp + ((size_t)(b * M + m0 + m)) * 64 + c4);
  }
  __syncthreads();
  const int c = t >> 2, ms = (t & 3) * 8;
  unsigned short* dst = vT + ((size_t)b * 64 + c) * M + m0 + ms;
  uint4 u;
  u.x = pk2(lds[(ms + 0) * 68 + c], lds[(ms + 1) * 68 + c]);
  u.y = pk2(lds[(ms + 2) * 68 + c], lds[(ms + 3) * 68 + c]);
  u.z = pk2(lds[(ms + 4) * 68 + c], lds[(ms + 5) * 68 + c]);
  u.w = pk2(lds[(ms + 6) * 68 + c], lds[(ms + 7) * 68 + c]);
  *reinterpret_cast<uint4*>(dst) = u;
}

__global__ __launch_bounds__(256) void tv_all(const float* __restrict__ v1p,
    unsigned short* __restrict__ vT1, const float* __restrict__ v2p,
    unsigned short* __restrict__ vT2) {
  __shared__ float lds[32 * 68];
  if (blockIdx.x < 32)
    tv_body<64>(blockIdx.x, v1p, vT1, lds);
  else
    tv_body<256>(blockIdx.x - 32, v2p, vT2, lds);
}

// ===== attention: HM=64 chunks (Pl 9.2 KiB); K2 in LDS, K1 global ==========
template <int M, int QOFF, bool K_LDS>
__device__ void attn_head(int b, int q0, int h,
    const unsigned short* __restrict__ qb, const unsigned short* Ks,
    const unsigned short* __restrict__ kbg, const unsigned short* __restrict__ vT,
    unsigned short* __restrict__ xc, unsigned short* Plw) {
  constexpr int HM = (M > 64) ? 64 : M;    // smaller P chunk -> small Pl
  constexpr int NCH = M / HM;
  constexpr int PSTR = HM + 8;             // 72: rows 16B-aligned, 2-way banks
  constexpr int MT = M / 16;
  constexpr int HKS = HM / 32;
  const int lane = threadIdx.x & 63;
  const int lrow = lane & 15, g = lane >> 4;
  const int lk = g * 8;
  const size_t bm = (size_t)b * M;
  const size_t qrow = ((size_t)b * 4096 + q0 + lrow) * 128;
  const int qoff = QOFF + h * 32;
  const float scale = 0.17677669529663687f;  // 1/sqrt(32)
  short8v qf = *reinterpret_cast<const short8v*>(qb + qrow + qoff + lk);
  f32x4 s[MT];
#pragma unroll
  for (int mt = 0; mt < MT; mt++) {
    short8v kf;
    if constexpr (K_LDS)
      kf = *reinterpret_cast<const short8v*>(
          Ks + (mt * 16 + lrow) * 72 + h * 32 + lk);
    else
      kf = *reinterpret_cast<const short8v*>(
          kbg + (bm + mt * 16 + lrow) * 64 + h * 32 + lk);
    s[mt] =
        __builtin_amdgcn_mfma_f32_16x16x32_bf16(kf, qf, (f32x4)(0.f), 0, 0, 0);
  }
  float l = 0.f;
#pragma unroll
  for (int mt = 0; mt < MT; mt++)
#pragma unroll
    for (int j = 0; j < 4; j++) {
      float p = __expf(s[mt][j] * scale);
      s[mt][j] = p;
      l += p;
    }
  l += __shfl_xor(l, 16, 64);
  l += __shfl_xor(l, 32, 64);
  f32x4 o[2];
  o[0] = (f32x4)(0.f);
  o[1] = (f32x4)(0.f);
#pragma unroll
  for (int half = 0; half < NCH; half++) {
#pragma unroll
    for (int mt2 = 0; mt2 < HM / 16; mt2++) {
      int mt = half * (HM / 16) + mt2;
      uint2 pw;
      pw.x = pk2(s[mt][0], s[mt][1]);
      pw.y = pk2(s[mt][2], s[mt][3]);
      *reinterpret_cast<uint2*>(&Plw[lrow * PSTR + mt2 * 16 + 4 * g]) = pw;
    }
    f32x4 oh[2];
    oh[0] = (f32x4)(0.f);
    oh[1] = (f32x4)(0.f);
#pragma unroll
    for (int ks = 0; ks < HKS; ks++) {
      short8v pf = *reinterpret_cast<const short8v*>(
          &Plw[lrow * PSTR + ks * 32 + lk]);
#pragma unroll
      for (int dt = 0; dt < 2; dt++) {
        short8v vf = *reinterpret_cast<const short8v*>(
            vT + ((size_t)b * 64 + h * 32 + dt * 16 + lrow) * M + half * HM +
            ks * 32 + lk);
        oh[dt] =
            __builtin_amdgcn_mfma_f32_16x16x32_bf16(vf, pf, oh[dt], 0, 0, 0);
      }
    }
#pragma unroll
    for (int dt = 0; dt < 2; dt++) o[dt] += oh[dt];
  }
  float linv = 1.f / l;
  unsigned short* orow = xc + qrow + qoff;
#pragma unroll
  for (int dt = 0; dt < 2; dt++) {
    uint2 u;
    u.x = pk2(o[dt][0] * linv, o[dt][1] * linv);
    u.y = pk2(o[dt][2] * linv, o[dt][3] * linv);
    *reinterpret_cast<uint2*>(orow + dt * 16 + 4 * g) = u;
  }
}

// one block per (b, 64 q-rows); 4 heads; LDS 46.1 KiB -> 3 blocks/CU
__global__ __launch_bounds__(256) void attn_all(
    const unsigned short* __restrict__ qb, const unsigned short* __restrict__ kb1,
    const unsigned short* __restrict__ vT1, const unsigned short* __restrict__ kb2,
    const unsigned short* __restrict__ vT2, unsigned short* __restrict__ xc) {
  __shared__ unsigned short Ks2[256 * 72];      // 36 KiB
  __shared__ unsigned short Pl[4 * 16 * 72];    // 9.2 KiB
  const int t = threadIdx.x;
  const int b = blockIdx.x >> 6, qt = blockIdx.x & 63;
  for (int i = t; i < 2048; i += 256) {
    int row = i >> 3, seg = i & 7;
    *reinterpret_cast<uint4*>(&Ks2[row * 72 + seg * 8]) =
        *reinterpret_cast<const uint4*>(kb2 + ((size_t)b * 256 + row) * 64 +
                                        seg * 8);
  }
  __syncthreads();
  const int wid = t >> 6;
  unsigned short* Plw = Pl + wid * 16 * 72;
  const int q0 = qt * 64 + wid * 16;
  attn_head<256, 64, true>(b, q0, 0, qb, Ks2, nullptr, vT2, xc, Plw);
  attn_head<256, 64, true>(b, q0, 1, qb, Ks2, nullptr, vT2, xc, Plw);
  attn_head<64, 0, false>(b, q0, 0, qb, nullptr, kb1, vT1, xc, Plw);
  attn_head<64, 0, false>(b, q0, 1, qb, nullptr, kb1, vT1, xc, Plw);
}

// ===== output projection ===================================================
__global__ __launch_bounds__(256) void proj(const unsigned short* __restrict__ A,
    const unsigned short* __restrict__ W, const float* __restrict__ bias,
    float* __restrict__ out) {
  gemm_body<true, false, true>(blockIdx.x, A, W, bias, out);
}

extern "C" void kernel_launch(void* const* d_in, const int* in_sizes, int n_in,
                              void* d_out, int out_size, void* d_ws,
                              size_t ws_size, hipStream_t stream) {
  (void)in_sizes; (void)n_in; (void)out_size; (void)ws_size;
  const float* x      = (const float*)d_in[0];
  const float* q_w    = (const float*)d_in[1];
  const float* sr1_w  = (const float*)d_in[2];
  const float* sr1_b  = (const float*)d_in[3];
  const float* n1_g   = (const float*)d_in[4];
  const float* n1_b   = (const float*)d_in[5];
  const float* sr2_w  = (const float*)d_in[6];
  const float* sr2_b  = (const float*)d_in[7];
  const float* n2_g   = (const float*)d_in[8];
  const float* n2_b   = (const float*)d_in[9];
  const float* kv1_w  = (const float*)d_in[10];
  const float* kv2_w  = (const float*)d_in[11];
  const float* lc1_w  = (const float*)d_in[12];
  const float* lc1_b  = (const float*)d_in[13];
  const float* lc2_w  = (const float*)d_in[14];
  const float* lc2_b  = (const float*)d_in[15];
  const float* proj_w = (const float*)d_in[16];
  const float* proj_b = (const float*)d_in[17];

  char* w = (char*)d_ws;
  unsigned short* wq    = (unsigned short*)(w);             // 32 KB
  unsigned short* wkv1  = (unsigned short*)(w + 32768);
  unsigned short* wkv2  = (unsigned short*)(w + 65536);
  unsigned short* wproj = (unsigned short*)(w + 98304);     // ends 131072
  unsigned short* w1b   = (unsigned short*)(w + 131072);    // 2 MB   -> 2228224
  unsigned short* w2b   = (unsigned short*)(w + 2228224);   // 512 KB -> 2752512
  unsigned short* xT  = (unsigned short*)(w + 2752512);     // 16.78 MB -> 19529728
  unsigned short* kb1 = (unsigned short*)(w + 19529728);    // 128 KB -> 19660800
  unsigned short* kb2 = (unsigned short*)(w + 19660800);    // 512 KB -> 20185088
  float* part1 = (float*)(w + 33685504);                    // 8.39 MB -> 42074112
  float* part2 = (float*)(w + 42074112);                    // 8.39 MB -> 50462720
  unsigned short* xcb = (unsigned short*)(w + 33685504);    // 16.78 MB (after ln)
  // xb: written by prep; q-GEMM transforms it IN PLACE into q (bf16).
  unsigned short* xb  = (unsigned short*)(w + 50462720);    // 16.78 MB -> 67239936
  unsigned short* qb  = xb;                                 // same buffer
  unsigned short* t1b = (unsigned short*)(w + 69468160);    // 256 KB -> 69730304
  unsigned short* t2b = (unsigned short*)(w + 69730304);    // 1 MB  -> 70778880
  float* vr1 = (float*)(w + 70778880);                      // 256 KB -> 71041024
  float* vr2 = (float*)(w + 71041024);                      // 1 MB  -> 72089600
  float* v1p = (float*)(w + 72089600);                      // 256 KB -> 72351744
  float* v2p = (float*)(w + 72351744);                      // 1 MB  -> 73400320
  unsigned short* vT1 = (unsigned short*)(w + 73400320);    // 128 KB -> 73531392
  unsigned short* vT2 = (unsigned short*)(w + 73531392);    // 512 KB -> 74055680

  prep<<<7424, 256, 0, stream>>>(x, xT, xb, q_w, kv1_w, kv2_w, proj_w, sr1_w,
                                 sr2_w, wq, wkv1, wkv2, wproj, w1b, w2b);
  conv_q<<<768, 256, 0, stream>>>(xT, w1b, w2b, part1, part2, xb, wq);
  ln_all<<<5120, 128, 0, stream>>>(part1, part2, sr1_b, n1_g, n1_b, sr2_b, n2_g,
                                   n2_b, t1b, t2b);
  kv_all<<<40, 256, 0, stream>>>(t1b, wkv1, kb1, vr1, t2b, wkv2, kb2, vr2);
  dw_all<<<1280, 256, 0, stream>>>(vr1, lc1_w, lc1_b, v1p, vr2, lc2_w, lc2_b, v2p);
  tv_all<<<160, 256, 0, stream>>>(v1p, vT1, v2p, vT2);
  attn_all<<<1024, 256, 0, stream>>>(qb, kb1, vT1, kb2, vT2, xcb);
  proj<<<512, 256, 0, stream>>>(xcb, wproj, proj_b, (float*)d_out);
}

// Round 23
// 116.720 us; speedup vs baseline: 1.0287x; 1.0173x over previous
//
#include <hip/hip_runtime.h>
#include <math.h>

#define B_ 16
#define N_ 4096

typedef __attribute__((ext_vector_type(8))) short short8v;
typedef __attribute__((ext_vector_type(4))) short short4v;
typedef __attribute__((ext_vector_type(4))) float f32x4;

__device__ __forceinline__ unsigned short f2bf(float f) {
  unsigned int u = __float_as_uint(f);
  return (unsigned short)((u + 0x7FFFu + ((u >> 16) & 1u)) >> 16);
}

__device__ __forceinline__ unsigned int pk2(float a, float b) {
  return (unsigned int)f2bf(a) | ((unsigned int)f2bf(b) << 16);
}

__device__ __forceinline__ short8v cvt8f(const float* p) {
  float4 a = *reinterpret_cast<const float4*>(p);
  float4 b = *reinterpret_cast<const float4*>(p + 4);
  short8v r;
  r[0] = (short)f2bf(a.x); r[1] = (short)f2bf(a.y);
  r[2] = (short)f2bf(a.z); r[3] = (short)f2bf(a.w);
  r[4] = (short)f2bf(b.x); r[5] = (short)f2bf(b.y);
  r[6] = (short)f2bf(b.z); r[7] = (short)f2bf(b.w);
  return r;
}

// ===== fused prep: x-transpose + bf16 row-copy (0..2047) + weight cvt ======
__global__ __launch_bounds__(256) void prep(const float* __restrict__ x,
    unsigned short* __restrict__ xT, unsigned short* __restrict__ xb,
    const float* __restrict__ a, const float* __restrict__ b,
    const float* __restrict__ c, const float* __restrict__ d,
    const float* __restrict__ s1, const float* __restrict__ s2,
    unsigned short* __restrict__ wa, unsigned short* __restrict__ wb,
    unsigned short* __restrict__ wc, unsigned short* __restrict__ wd,
    unsigned short* __restrict__ w1, unsigned short* __restrict__ w2) {
  __shared__ float lds[32 * 132];
  const int t = threadIdx.x;
  if (blockIdx.x < 2048) {
    const int bb = blockIdx.x >> 7, pt = blockIdx.x & 127;
    const int ptile = pt * 32;
    for (int i = t; i < 1024; i += 256) {
      int p = i >> 5, c4 = (i & 31) << 2;
      *reinterpret_cast<float4*>(&lds[p * 132 + c4]) =
          *reinterpret_cast<const float4*>(
              x + ((size_t)(bb * 4096 + ptile + p)) * 128 + c4);
    }
    __syncthreads();
    // bf16 row-major copy (coalesced uint2)
    for (int i = t; i < 1024; i += 256) {
      int p = i >> 5, c4 = (i & 31) << 2;
      const float* s = &lds[p * 132 + c4];
      uint2 u;
      u.x = pk2(s[0], s[1]);
      u.y = pk2(s[2], s[3]);
      *reinterpret_cast<uint2*>(
          xb + ((size_t)(bb * 4096 + ptile + p)) * 128 + c4) = u;
    }
    // transpose to xT
    const int ch = t >> 1, p0 = (t & 1) * 16;
    unsigned short* dst = xT + (size_t)bb * 524288 + ch * 4096 + ptile + p0;
    uint4 u0, u1;
    u0.x = pk2(lds[(p0 + 0) * 132 + ch], lds[(p0 + 1) * 132 + ch]);
    u0.y = pk2(lds[(p0 + 2) * 132 + ch], lds[(p0 + 3) * 132 + ch]);
    u0.z = pk2(lds[(p0 + 4) * 132 + ch], lds[(p0 + 5) * 132 + ch]);
    u0.w = pk2(lds[(p0 + 6) * 132 + ch], lds[(p0 + 7) * 132 + ch]);
    u1.x = pk2(lds[(p0 + 8) * 132 + ch], lds[(p0 + 9) * 132 + ch]);
    u1.y = pk2(lds[(p0 + 10) * 132 + ch], lds[(p0 + 11) * 132 + ch]);
    u1.z = pk2(lds[(p0 + 12) * 132 + ch], lds[(p0 + 13) * 132 + ch]);
    u1.w = pk2(lds[(p0 + 14) * 132 + ch], lds[(p0 + 15) * 132 + ch]);
    *reinterpret_cast<uint4*>(dst) = u0;
    *reinterpret_cast<uint4*>(dst + 8) = u1;
  } else {
    int i = (blockIdx.x - 2048) * 256 + t;
    if (i < 16384) wa[i] = f2bf(a[i]);
    else if (i < 32768) { int o = i - 16384; wb[o] = f2bf(b[o]); }
    else if (i < 49152) { int o = i - 32768; wc[o] = f2bf(c[o]); }
    else if (i < 65536) { int o = i - 49152; wd[o] = f2bf(d[o]); }
    else if (i < 65536 + 1048576) { int o = i - 65536; w1[o] = f2bf(s1[o]); }
    else { int o = i - 65536 - 1048576; w2[o] = f2bf(s2[o]); }  // 262144
  }
}

// ===== conv body (R13 exact, decoded indices) ==============================
template <int SRV, int KSP>
__device__ void conv_body(int bx, int by, const unsigned short* __restrict__ xT,
    const unsigned short* __restrict__ W, float* __restrict__ part) {
  constexpr int WP = 64 / SRV;
  constexpr int M = WP * WP;
  constexpr int ROWS = B_ * M;
  constexpr int SS = SRV * SRV;
  constexpr int KTOT = 128 * SS;
  constexpr int LSS = (SRV == 8) ? 6 : 4;
  constexpr int LM = (SRV == 8) ? 6 : 8;
  constexpr int LWP = (SRV == 8) ? 3 : 4;
  const int t = threadIdx.x;
  const int wid = t >> 6, lane = t & 63;
  const int lrow = lane & 15, lk = (lane >> 4) << 3;
  const int r0 = bx * 128 + wid * 32;
  const int kb0 = by * KSP;
  int rbase[2], pixoff[2];
#pragma unroll
  for (int m = 0; m < 2; m++) {
    int row = r0 + m * 16 + lrow;
    int b = row >> LM, p = row & (M - 1);
    int ph = p >> LWP, pw = p & (WP - 1);
    rbase[m] = b << 19;
    pixoff[m] = (ph * SRV) * 64 + pw * SRV;
  }
  f32x4 acc[2][8];
#pragma unroll
  for (int m = 0; m < 2; m++)
#pragma unroll
    for (int n = 0; n < 8; n++) acc[m][n] = (f32x4)(0.f);
  for (int k0 = 0; k0 < KSP; k0 += 32) {
    int k = kb0 + k0 + lk;
    int ci = k >> LSS;
    int rem = k & (SS - 1);
    short8v a[2], bf[8];
#pragma unroll
    for (int m = 0; m < 2; m++) {
      if constexpr (SRV == 8) {
        a[m] = *reinterpret_cast<const short8v*>(
            xT + (size_t)rbase[m] + ci * 4096 + pixoff[m] + (rem >> 3) * 64);
      } else {
        int kh0 = rem >> 2;
        short4v lo = *reinterpret_cast<const short4v*>(
            xT + (size_t)rbase[m] + ci * 4096 + pixoff[m] + kh0 * 64);
        short4v hi = *reinterpret_cast<const short4v*>(
            xT + (size_t)rbase[m] + ci * 4096 + pixoff[m] + (kh0 + 1) * 64);
        short8v av;
        av[0] = lo[0]; av[1] = lo[1]; av[2] = lo[2]; av[3] = lo[3];
        av[4] = hi[0]; av[5] = hi[1]; av[6] = hi[2]; av[7] = hi[3];
        a[m] = av;
      }
    }
#pragma unroll
    for (int n = 0; n < 8; n++)
      bf[n] = *reinterpret_cast<const short8v*>(
          W + (size_t)(n * 16 + lrow) * KTOT + k);
#pragma unroll
    for (int m = 0; m < 2; m++)
#pragma unroll
      for (int n = 0; n < 8; n++)
        acc[m][n] = __builtin_amdgcn_mfma_f32_16x16x32_bf16(a[m], bf[n],
                                                            acc[m][n], 0, 0, 0);
  }
  const int rr = (lane >> 4) << 2;
#pragma unroll
  for (int m = 0; m < 2; m++)
#pragma unroll
    for (int n = 0; n < 8; n++) {
      int cc = n * 16 + lrow;
#pragma unroll
      for (int j = 0; j < 4; j++)
        part[((size_t)by * ROWS + r0 + m * 16 + rr + j) * 128 + cc] =
            acc[m][n][j];
    }
}

// ===== square GEMM body (R13 exact) ========================================
template <bool A_BF16, bool OUT_BF16, bool HAS_BIAS>
__device__ void gemm_body(int bx, const void* __restrict__ Araw,
    const unsigned short* __restrict__ W, const float* __restrict__ bias,
    void* __restrict__ out) {
  const int t = threadIdx.x;
  const int wid = t >> 6, lane = t & 63;
  const int lrow = lane & 15, lk = (lane >> 4) << 3;
  const int r0 = bx * 128 + wid * 32;
  f32x4 acc[2][8];
#pragma unroll
  for (int m = 0; m < 2; m++)
#pragma unroll
    for (int n = 0; n < 8; n++) acc[m][n] = (f32x4)(0.f);
#pragma unroll
  for (int k0 = 0; k0 < 128; k0 += 32) {
    short8v a[2], bf[8];
#pragma unroll
    for (int m = 0; m < 2; m++) {
      if constexpr (A_BF16)
        a[m] = *reinterpret_cast<const short8v*>(
            (const unsigned short*)Araw + (size_t)(r0 + m * 16 + lrow) * 128 +
            k0 + lk);
      else
        a[m] = cvt8f((const float*)Araw + (size_t)(r0 + m * 16 + lrow) * 128 +
                     k0 + lk);
    }
#pragma unroll
    for (int n = 0; n < 8; n++)
      bf[n] = *reinterpret_cast<const short8v*>(
          W + (size_t)(n * 16 + lrow) * 128 + k0 + lk);
#pragma unroll
    for (int m = 0; m < 2; m++)
#pragma unroll
      for (int n = 0; n < 8; n++)
        acc[m][n] = __builtin_amdgcn_mfma_f32_16x16x32_bf16(a[m], bf[n],
                                                            acc[m][n], 0, 0, 0);
  }
  const int rr = (lane >> 4) << 2;
#pragma unroll
  for (int m = 0; m < 2; m++)
#pragma unroll
    for (int n = 0; n < 8; n++) {
      int cc = n * 16 + lrow;
      float bv = HAS_BIAS ? bias[cc] : 0.f;
#pragma unroll
      for (int j = 0; j < 4; j++) {
        size_t idx = (size_t)(r0 + m * 16 + rr + j) * 128 + cc;
        float v = acc[m][n][j] + bv;
        if constexpr (OUT_BF16)
          ((unsigned short*)out)[idx] = f2bf(v);
        else
          ((float*)out)[idx] = v;
      }
    }
}

// ===== fused conv1 + conv2 + q-gemm (KSP=512; q-gemm IN-PLACE on xb) =======
__global__ __launch_bounds__(256) void conv_q(
    const unsigned short* __restrict__ xT, const unsigned short* __restrict__ w1b,
    const unsigned short* __restrict__ w2b, float* __restrict__ part1,
    float* __restrict__ part2, unsigned short* __restrict__ xb,
    const unsigned short* __restrict__ wq) {
  const int bid = blockIdx.x;
  if (bid < 128) {
    conv_body<8, 512>(bid & 7, bid >> 3, xT, w1b, part1);
  } else if (bid < 256) {
    int j = bid - 128;
    conv_body<4, 512>(j & 31, j >> 5, xT, w2b, part2);
  } else {
    // in-place: block reads rows [r0,r0+128) of xb fully, then writes them
    gemm_body<true, true, false>(bid - 256, xb, wq, nullptr, xb);
  }
}

// ===== fused LN+GELU over both branches (nsplit 16 / 4) ====================
__global__ __launch_bounds__(128) void ln_all(const float* __restrict__ part1,
    const float* __restrict__ part2, const float* __restrict__ cb1,
    const float* __restrict__ g1, const float* __restrict__ be1,
    const float* __restrict__ cb2, const float* __restrict__ g2,
    const float* __restrict__ be2, unsigned short* __restrict__ out1,
    unsigned short* __restrict__ out2) {
  const int t = threadIdx.x;
  int row = blockIdx.x;
  const float* part; const float *cb, *g, *be; unsigned short* out;
  int nsplit, rows;
  if (row < 1024) {
    part = part1; cb = cb1; g = g1; be = be1; out = out1;
    nsplit = 16; rows = 1024;
  } else {
    row -= 1024;
    part = part2; cb = cb2; g = g2; be = be2; out = out2;
    nsplit = 4; rows = 4096;
  }
  float v = cb[t];
  for (int s = 0; s < nsplit; s++)
    v += part[((size_t)s * rows + row) * 128 + t];
  float sv = v, sq = v * v;
#pragma unroll
  for (int off = 32; off > 0; off >>= 1) {
    sv += __shfl_down(sv, off, 64);
    sq += __shfl_down(sq, off, 64);
  }
  __shared__ float red0[2], red1[2];
  if ((t & 63) == 0) {
    red0[t >> 6] = sv;
    red1[t >> 6] = sq;
  }
  __syncthreads();
  float mean = (red0[0] + red0[1]) * (1.f / 128.f);
  float var = (red1[0] + red1[1]) * (1.f / 128.f) - mean * mean;
  float y = (v - mean) * rsqrtf(var + 1e-5f) * g[t] + be[t];
  out[(size_t)row * 128 + t] = f2bf(y * 0.5f * (1.f + erff(y * 0.70710678118f)));
}

// ===== kv GEMM body (split epilogue, R13 exact) ============================
__device__ void kv_body(int bx, const unsigned short* __restrict__ A,
    const unsigned short* __restrict__ W, unsigned short* __restrict__ kb,
    float* __restrict__ vr) {
  const int t = threadIdx.x;
  const int wid = t >> 6, lane = t & 63;
  const int lrow = lane & 15, lk = (lane >> 4) << 3;
  const int r0 = bx * 128 + wid * 32;
  f32x4 acc[2][8];
#pragma unroll
  for (int m = 0; m < 2; m++)
#pragma unroll
    for (int n = 0; n < 8; n++) acc[m][n] = (f32x4)(0.f);
#pragma unroll
  for (int k0 = 0; k0 < 128; k0 += 32) {
    short8v a[2], bf[8];
#pragma unroll
    for (int m = 0; m < 2; m++)
      a[m] = *reinterpret_cast<const short8v*>(
          A + (size_t)(r0 + m * 16 + lrow) * 128 + k0 + lk);
#pragma unroll
    for (int n = 0; n < 8; n++)
      bf[n] = *reinterpret_cast<const short8v*>(
          W + (size_t)(n * 16 + lrow) * 128 + k0 + lk);
#pragma unroll
    for (int m = 0; m < 2; m++)
#pragma unroll
      for (int n = 0; n < 8; n++)
        acc[m][n] = __builtin_amdgcn_mfma_f32_16x16x32_bf16(a[m], bf[n],
                                                            acc[m][n], 0, 0, 0);
  }
  const int rr = (lane >> 4) << 2;
#pragma unroll
  for (int m = 0; m < 2; m++)
#pragma unroll
    for (int n = 0; n < 8; n++) {
      int cc = n * 16 + lrow;
#pragma unroll
      for (int j = 0; j < 4; j++) {
        int r = r0 + m * 16 + rr + j;
        float v = acc[m][n][j];
        if (cc < 64)
          kb[(size_t)r * 64 + cc] = f2bf(v);
        else
          vr[(size_t)r * 64 + (cc - 64)] = v;
      }
    }
}

__global__ __launch_bounds__(256) void kv_all(
    const unsigned short* __restrict__ t1b, const unsigned short* __restrict__ wkv1,
    unsigned short* __restrict__ kb1, float* __restrict__ vr1,
    const unsigned short* __restrict__ t2b, const unsigned short* __restrict__ wkv2,
    unsigned short* __restrict__ kb2, float* __restrict__ vr2) {
  if (blockIdx.x < 8)
    kv_body(blockIdx.x, t1b, wkv1, kb1, vr1);
  else
    kv_body(blockIdx.x - 8, t2b, wkv2, kb2, vr2);
}

// ===== dwconv body (R13 exact) =============================================
template <int WP>
__device__ void dw_body(int idx, const float* __restrict__ vr,
    const float* __restrict__ lw, const float* __restrict__ lb,
    float* __restrict__ vp) {
  constexpr int M = WP * WP;
  constexpr int LM = (WP == 8) ? 6 : 8;
  constexpr int LWPc = (WP == 8) ? 3 : 4;
  int ch = idx & 63;
  int rest = idx >> 6;
  int m = rest & (M - 1);
  int bb = rest >> LM;
  int y = m >> LWPc, x0 = m & (WP - 1);
  float s = lb[ch];
#pragma unroll
  for (int ky = 0; ky < 3; ky++) {
    int yy = y + ky - 1;
    if (yy < 0 || yy >= WP) continue;
#pragma unroll
    for (int kx = 0; kx < 3; kx++) {
      int xx = x0 + kx - 1;
      if (xx < 0 || xx >= WP) continue;
      s += vr[((size_t)(bb * M + yy * WP + xx)) * 64 + ch] *
           lw[ch * 9 + ky * 3 + kx];
    }
  }
  vp[idx] = vr[((size_t)(bb * M + m)) * 64 + ch] + s;
}

__global__ __launch_bounds__(256) void dw_all(const float* __restrict__ vr1,
    const float* __restrict__ lw1, const float* __restrict__ lb1,
    float* __restrict__ v1p, const float* __restrict__ vr2,
    const float* __restrict__ lw2, const float* __restrict__ lb2,
    float* __restrict__ v2p) {
  if (blockIdx.x < 256)
    dw_body<8>(blockIdx.x * 256 + threadIdx.x, vr1, lw1, lb1, v1p);
  else
    dw_body<16>((blockIdx.x - 256) * 256 + threadIdx.x, vr2, lw2, lb2, v2p);
}

// ===== v-transpose body (R13 exact) ========================================
template <int M>
__device__ void tv_body(int blk, const float* __restrict__ vp,
    unsigned short* __restrict__ vT, float* lds) {
  constexpr int TPB = M / 32;
  const int t = threadIdx.x;
  const int b = blk / TPB, mt = blk % TPB;
  const int m0 = mt * 32;
  for (int i = t; i < 512; i += 256) {
    int m = i >> 4, c4 = (i & 15) << 2;
    *reinterpret_cast<float4*>(&lds[m * 68 + c4]) =
        *reinterpret_cast<const float4*>(vp + ((size_t)(b * M + m0 + m)) * 64 + c4);
  }
  __syncthreads();
  const int c = t >> 2, ms = (t & 3) * 8;
  unsigned short* dst = vT + ((size_t)b * 64 + c) * M + m0 + ms;
  uint4 u;
  u.x = pk2(lds[(ms + 0) * 68 + c], lds[(ms + 1) * 68 + c]);
  u.y = pk2(lds[(ms + 2) * 68 + c], lds[(ms + 3) * 68 + c]);
  u.z = pk2(lds[(ms + 4) * 68 + c], lds[(ms + 5) * 68 + c]);
  u.w = pk2(lds[(ms + 6) * 68 + c], lds[(ms + 7) * 68 + c]);
  *reinterpret_cast<uint4*>(dst) = u;
}

__global__ __launch_bounds__(256) void tv_all(const float* __restrict__ v1p,
    unsigned short* __restrict__ vT1, const float* __restrict__ v2p,
    unsigned short* __restrict__ vT2) {
  __shared__ float lds[32 * 68];
  if (blockIdx.x < 32)
    tv_body<64>(blockIdx.x, v1p, vT1, lds);
  else
    tv_body<256>(blockIdx.x - 32, v2p, vT2, lds);
}

// ===== attention head: output -> wave-private LDS Po[16][136] (bf16) =======
template <int M, int QOFF, bool K_LDS>
__device__ void attn_head(int b, int q0, int h,
    const unsigned short* __restrict__ qb, const unsigned short* Ks,
    const unsigned short* __restrict__ kbg, const unsigned short* __restrict__ vT,
    unsigned short* Pow, unsigned short* Plw) {
  constexpr int HM = (M > 64) ? 64 : M;
  constexpr int NCH = M / HM;
  constexpr int PSTR = HM + 8;             // 72
  constexpr int MT = M / 16;
  constexpr int HKS = HM / 32;
  const int lane = threadIdx.x & 63;
  const int lrow = lane & 15, g = lane >> 4;
  const int lk = g * 8;
  const size_t bm = (size_t)b * M;
  const size_t qrow = ((size_t)b * 4096 + q0 + lrow) * 128;
  const int qoff = QOFF + h * 32;
  const float scale = 0.17677669529663687f;  // 1/sqrt(32)
  short8v qf = *reinterpret_cast<const short8v*>(qb + qrow + qoff + lk);
  f32x4 s[MT];
#pragma unroll
  for (int mt = 0; mt < MT; mt++) {
    short8v kf;
    if constexpr (K_LDS)
      kf = *reinterpret_cast<const short8v*>(
          Ks + (mt * 16 + lrow) * 72 + h * 32 + lk);
    else
      kf = *reinterpret_cast<const short8v*>(
          kbg + (bm + mt * 16 + lrow) * 64 + h * 32 + lk);
    s[mt] =
        __builtin_amdgcn_mfma_f32_16x16x32_bf16(kf, qf, (f32x4)(0.f), 0, 0, 0);
  }
  float l = 0.f;
#pragma unroll
  for (int mt = 0; mt < MT; mt++)
#pragma unroll
    for (int j = 0; j < 4; j++) {
      float p = __expf(s[mt][j] * scale);
      s[mt][j] = p;
      l += p;
    }
  l += __shfl_xor(l, 16, 64);
  l += __shfl_xor(l, 32, 64);
  f32x4 o[2];
  o[0] = (f32x4)(0.f);
  o[1] = (f32x4)(0.f);
#pragma unroll
  for (int half = 0; half < NCH; half++) {
#pragma unroll
    for (int mt2 = 0; mt2 < HM / 16; mt2++) {
      int mt = half * (HM / 16) + mt2;
      uint2 pw;
      pw.x = pk2(s[mt][0], s[mt][1]);
      pw.y = pk2(s[mt][2], s[mt][3]);
      *reinterpret_cast<uint2*>(&Plw[lrow * PSTR + mt2 * 16 + 4 * g]) = pw;
    }
    f32x4 oh[2];
    oh[0] = (f32x4)(0.f);
    oh[1] = (f32x4)(0.f);
#pragma unroll
    for (int ks = 0; ks < HKS; ks++) {
      short8v pf = *reinterpret_cast<const short8v*>(
          &Plw[lrow * PSTR + ks * 32 + lk]);
#pragma unroll
      for (int dt = 0; dt < 2; dt++) {
        short8v vf = *reinterpret_cast<const short8v*>(
            vT + ((size_t)b * 64 + h * 32 + dt * 16 + lrow) * M + half * HM +
            ks * 32 + lk);
        oh[dt] =
            __builtin_amdgcn_mfma_f32_16x16x32_bf16(vf, pf, oh[dt], 0, 0, 0);
      }
    }
#pragma unroll
    for (int dt = 0; dt < 2; dt++) o[dt] += oh[dt];
  }
  // write this head's 32 cols into wave-private Po (row = q-col lrow)
  float linv = 1.f / l;
#pragma unroll
  for (int dt = 0; dt < 2; dt++) {
    uint2 u;
    u.x = pk2(o[dt][0] * linv, o[dt][1] * linv);
    u.y = pk2(o[dt][2] * linv, o[dt][3] * linv);
    *reinterpret_cast<uint2*>(&Pow[lrow * 136 + qoff + dt * 16 + 4 * g]) = u;
  }
}

// one block per (b, 64 q-rows); 4 heads + fused output projection
__global__ __launch_bounds__(256) void attn_all(
    const unsigned short* __restrict__ qb, const unsigned short* __restrict__ kb1,
    const unsigned short* __restrict__ vT1, const unsigned short* __restrict__ kb2,
    const unsigned short* __restrict__ vT2,
    const unsigned short* __restrict__ wproj, const float* __restrict__ pb,
    float* __restrict__ out) {
  __shared__ unsigned short Ks2[256 * 72];      // 36 KiB
  __shared__ unsigned short Pl[4 * 16 * 72];    // 9.2 KiB
  __shared__ unsigned short Po[4 * 16 * 136];   // 17.4 KiB  (total 62 KiB)
  const int t = threadIdx.x;
  const int b = blockIdx.x >> 6, qt = blockIdx.x & 63;
  for (int i = t; i < 2048; i += 256) {
    int row = i >> 3, seg = i & 7;
    *reinterpret_cast<uint4*>(&Ks2[row * 72 + seg * 8]) =
        *reinterpret_cast<const uint4*>(kb2 + ((size_t)b * 256 + row) * 64 +
                                        seg * 8);
  }
  __syncthreads();
  const int wid = t >> 6, lane = t & 63;
  const int lrow = lane & 15, g = lane >> 4;
  const int lk = g * 8;
  unsigned short* Plw = Pl + wid * 16 * 72;
  unsigned short* Pow = Po + wid * 16 * 136;
  const int q0 = qt * 64 + wid * 16;
  attn_head<256, 64, true>(b, q0, 0, qb, Ks2, nullptr, vT2, Pow, Plw);
  attn_head<256, 64, true>(b, q0, 1, qb, Ks2, nullptr, vT2, Pow, Plw);
  attn_head<64, 0, false>(b, q0, 0, qb, nullptr, kb1, vT1, Pow, Plw);
  attn_head<64, 0, false>(b, q0, 1, qb, nullptr, kb1, vT1, Pow, Plw);
  // ---- fused projection: this wave's 16 rows x 128 cols (no barrier:
  // Po is wave-private and LDS ops are in-order within a wave) ----
  f32x4 pacc[8];
#pragma unroll
  for (int n = 0; n < 8; n++) pacc[n] = (f32x4)(0.f);
#pragma unroll
  for (int k0 = 0; k0 < 128; k0 += 32) {
    short8v a = *reinterpret_cast<const short8v*>(&Pow[lrow * 136 + k0 + lk]);
    short8v bf[8];
#pragma unroll
    for (int n = 0; n < 8; n++)
      bf[n] = *reinterpret_cast<const short8v*>(
          wproj + (size_t)(n * 16 + lrow) * 128 + k0 + lk);
#pragma unroll
    for (int n = 0; n < 8; n++)
      pacc[n] = __builtin_amdgcn_mfma_f32_16x16x32_bf16(a, bf[n], pacc[n],
                                                        0, 0, 0);
  }
  const int rr = g * 4;
#pragma unroll
  for (int n = 0; n < 8; n++) {
    int cc = n * 16 + lrow;
    float bv = pb[cc];
#pragma unroll
    for (int j = 0; j < 4; j++)
      out[(size_t)(b * 4096 + q0 + rr + j) * 128 + cc] = pacc[n][j] + bv;
  }
}

extern "C" void kernel_launch(void* const* d_in, const int* in_sizes, int n_in,
                              void* d_out, int out_size, void* d_ws,
                              size_t ws_size, hipStream_t stream) {
  (void)in_sizes; (void)n_in; (void)out_size; (void)ws_size;
  const float* x      = (const float*)d_in[0];
  const float* q_w    = (const float*)d_in[1];
  const float* sr1_w  = (const float*)d_in[2];
  const float* sr1_b  = (const float*)d_in[3];
  const float* n1_g   = (const float*)d_in[4];
  const float* n1_b   = (const float*)d_in[5];
  const float* sr2_w  = (const float*)d_in[6];
  const float* sr2_b  = (const float*)d_in[7];
  const float* n2_g   = (const float*)d_in[8];
  const float* n2_b   = (const float*)d_in[9];
  const float* kv1_w  = (const float*)d_in[10];
  const float* kv2_w  = (const float*)d_in[11];
  const float* lc1_w  = (const float*)d_in[12];
  const float* lc1_b  = (const float*)d_in[13];
  const float* lc2_w  = (const float*)d_in[14];
  const float* lc2_b  = (const float*)d_in[15];
  const float* proj_w = (const float*)d_in[16];
  const float* proj_b = (const float*)d_in[17];

  char* w = (char*)d_ws;
  unsigned short* wq    = (unsigned short*)(w);             // 32 KB
  unsigned short* wkv1  = (unsigned short*)(w + 32768);
  unsigned short* wkv2  = (unsigned short*)(w + 65536);
  unsigned short* wproj = (unsigned short*)(w + 98304);     // ends 131072
  unsigned short* w1b   = (unsigned short*)(w + 131072);    // 2 MB   -> 2228224
  unsigned short* w2b   = (unsigned short*)(w + 2228224);   // 512 KB -> 2752512
  unsigned short* xT  = (unsigned short*)(w + 2752512);     // 16.78 MB -> 19529728
  unsigned short* kb1 = (unsigned short*)(w + 19529728);    // 128 KB -> 19660800
  unsigned short* kb2 = (unsigned short*)(w + 19660800);    // 512 KB -> 20185088
  float* part1 = (float*)(w + 33685504);                    // 8.39 MB -> 42074112
  float* part2 = (float*)(w + 42074112);                    // 8.39 MB -> 50462720
  // xb: written by prep; q-GEMM transforms it IN PLACE into q (bf16).
  unsigned short* xb  = (unsigned short*)(w + 50462720);    // 16.78 MB -> 67239936
  unsigned short* qb  = xb;                                 // same buffer
  unsigned short* t1b = (unsigned short*)(w + 69468160);    // 256 KB -> 69730304
  unsigned short* t2b = (unsigned short*)(w + 69730304);    // 1 MB  -> 70778880
  float* vr1 = (float*)(w + 70778880);                      // 256 KB -> 71041024
  float* vr2 = (float*)(w + 71041024);                      // 1 MB  -> 72089600
  float* v1p = (float*)(w + 72089600);                      // 256 KB -> 72351744
  float* v2p = (float*)(w + 72351744);                      // 1 MB  -> 73400320
  unsigned short* vT1 = (unsigned short*)(w + 73400320);    // 128 KB -> 73531392
  unsigned short* vT2 = (unsigned short*)(w + 73531392);    // 512 KB -> 74055680

  prep<<<7424, 256, 0, stream>>>(x, xT, xb, q_w, kv1_w, kv2_w, proj_w, sr1_w,
                                 sr2_w, wq, wkv1, wkv2, wproj, w1b, w2b);
  conv_q<<<768, 256, 0, stream>>>(xT, w1b, w2b, part1, part2, xb, wq);
  ln_all<<<5120, 128, 0, stream>>>(part1, part2, sr1_b, n1_g, n1_b, sr2_b, n2_g,
                                   n2_b, t1b, t2b);
  kv_all<<<40, 256, 0, stream>>>(t1b, wkv1, kb1, vr1, t2b, wkv2, kb2, vr2);
  dw_all<<<1280, 256, 0, stream>>>(vr1, lc1_w, lc1_b, v1p, vr2, lc2_w, lc2_b, v2p);
  tv_all<<<160, 256, 0, stream>>>(v1p, vT1, v2p, vT2);
  // attention + fused output projection -> d_out
  attn_all<<<1024, 256, 0, stream>>>(qb, kb1, vT1, kb2, vT2, wproj, proj_b,
                                     (float*)d_out);
}